// Round 25
// baseline (101.254 us; speedup 1.0000x reference)
//
#include <hip/hip_runtime.h>

#define BB 2048
#define FF 256
#define EE 257
#define UU 64
#define HH1 64
#define HH2 32

// SC = log2(e) / sqrt(E): folds softmax temperature into log2-domain for exp2f
#define SC 0.089992807f

typedef __attribute__((ext_vector_type(8))) short short8;   // 8 bf16 (4 VGPR)
typedef __attribute__((ext_vector_type(4))) float f32x4;    // MFMA acc
typedef __attribute__((ext_vector_type(4))) unsigned u32x4;
typedef __attribute__((ext_vector_type(2))) unsigned u32x2;

#define MF(a, b, c) __builtin_amdgcn_mfma_f32_16x16x32_bf16(a, b, c, 0, 0, 0)
#define EXP2(x) __builtin_amdgcn_exp2f(x)   // bare v_exp_f32 (scores bounded, no fixup needed)

__device__ inline unsigned cvt_pk(float a, float b) {       // packed RNE: lo=bf16(a), hi=bf16(b)
    unsigned r;
    asm("v_cvt_pk_bf16_f32 %0, %1, %2" : "=v"(r) : "v"(a), "v"(b));
    return r;
}
struct HiLo { unsigned hi, lo; };
// hi/lo split of a pair: hi = bf16(a,b); lo = bf16(a-hi_a, b-hi_b)
__device__ inline HiLo split2(float a, float b) {
    HiLo r;
    r.hi = cvt_pk(a, b);
    float ha = __builtin_bit_cast(float, r.hi << 16);
    float hb = __builtin_bit_cast(float, r.hi & 0xFFFF0000u);
    r.lo = cvt_pk(a - ha, b - hb);
    return r;
}

// ---------------- K_prep (pair-packed mt, pi-permuted W2) ----------------
__global__ __launch_bounds__(256) void k_prep(const float* __restrict__ in_w,
                                              const float* __restrict__ in_b,
                                              const float* __restrict__ out_w,
                                              const float* __restrict__ out_b,
                                              const float* __restrict__ w2,
                                              const float* __restrict__ w3,
                                              float* __restrict__ mt,      // paired float2 layout
                                              float* __restrict__ uv, float* __restrict__ wgf,
                                              float* __restrict__ sc,
                                              short* __restrict__ w2s, short* __restrict__ w3s) {
    const int blk = blockIdx.x;
    const int t = threadIdx.x;
    __shared__ float red[4][256];
    __shared__ float s0[EE + 3];   // staged uniform stream A
    __shared__ float s1[EE + 3];   // staged uniform stream B
    if (blk < 256) {
        const int ki = blk;
        for (int j = t; j < EE; j += 256) {
            s0[j] = in_w[(EE + j) * EE + ki] + in_b[EE + j];
            s1[j] = in_b[j];
        }
        __syncthreads();
        const int w = t >> 6, l = t & 63;
        const int j0 = (w * EE) >> 2, j1 = ((w + 1) * EE) >> 2;
        float acc[4] = {0.f, 0.f, 0.f, 0.f};
#pragma unroll 4
        for (int j = j0; j < j1; ++j) {
            float ak = s0[j];   // LDS broadcast
            float bj = s1[j];
#pragma unroll
            for (int g = 0; g < 4; ++g) {
                float aq = in_w[j * EE + l + 64 * g] + bj;
                acc[g] = fmaf(aq, ak, acc[g]);
            }
        }
#pragma unroll
        for (int g = 0; g < 4; ++g) red[w][l + 64 * g] = acc[g];
        __syncthreads();
        {
            float s = red[0][t] + red[1][t] + red[2][t] + red[3][t];
            mt[(ki >> 1) * 512 + t * 2 + (ki & 1)] = s * SC;
        }
    } else if (blk < 512) {
        const int f = blk - 256;
        const int l = t & 63, q = t >> 6;
        const int lr = l & 15, lq = l >> 4;
        const float* w2f = w2 + f * (UU * HH1);
        const float* w3f = w3 + f * (HH1 * HH2);
        short* o2 = w2s + f * 8192;
        short* o3 = w3s + f * 4096;
        // pi-permuted h column for the W2 A-frag row (q = ht tile, lr = row-in-tile)
        const int hperm = (q & 1) * 32 + (lr >> 2) * 8 + ((q >> 1) << 2) + (lr & 3);
#pragma unroll
        for (int kb = 0; kb < 2; ++kb) {
            float v[8];
#pragma unroll
            for (int j = 0; j < 8; ++j) v[j] = w2f[(kb * 32 + lq * 8 + j) * HH1 + hperm];
            u32x4 hi, lo;
#pragma unroll
            for (int p = 0; p < 4; ++p) {
                HiLo s = split2(v[2 * p], v[2 * p + 1]);
                hi[p] = s.hi; lo[p] = s.lo;
            }
            *(short8*)(o2 + ((0 * 2 + kb) * 4 + q) * 512 + l * 8) = __builtin_bit_cast(short8, hi);
            *(short8*)(o2 + ((1 * 2 + kb) * 4 + q) * 512 + l * 8) = __builtin_bit_cast(short8, lo);
        }
        {
            const int kb = q & 1, ct = q >> 1;
            float v[8];
#pragma unroll
            for (int j = 0; j < 8; ++j) v[j] = w3f[(kb * 32 + lq * 8 + j) * HH2 + ct * 16 + lr];
            u32x4 hi, lo;
#pragma unroll
            for (int p = 0; p < 4; ++p) {
                HiLo s = split2(v[2 * p], v[2 * p + 1]);
                hi[p] = s.hi; lo[p] = s.lo;
            }
            *(short8*)(o3 + ((0 * 2 + kb) * 2 + ct) * 512 + l * 8) = __builtin_bit_cast(short8, hi);
            *(short8*)(o3 + ((1 * 2 + kb) * 2 + ct) * 512 + l * 8) = __builtin_bit_cast(short8, lo);
        }
    } else if (blk < 515) {
        const int which = blk - 512;
        for (int j = t; j < EE; j += 256) {
            if (which == 0)      { s0[j] = in_w[(EE + j) * EE + FF];    s1[j] = in_b[j]; }
            else if (which == 1) { s0[j] = in_w[j * EE + FF];           s1[j] = in_b[EE + j]; }
            else                 { s0[j] = out_w[(EE - 1) * EE + j];    s1[j] = in_b[2 * EE + j]; }
        }
        __syncthreads();
        const int w = t >> 6, l = t & 63;
        const int j0 = (w * EE) >> 2, j1 = ((w + 1) * EE) >> 2;
        const int rowbase = which * EE;
        float acc[4] = {0.f, 0.f, 0.f, 0.f};
#pragma unroll 4
        for (int j = j0; j < j1; ++j) {
            float sk = s0[j];
            float bj = s1[j];
#pragma unroll
            for (int g = 0; g < 4; ++g) {
                float av = in_w[(rowbase + j) * EE + l + 64 * g] + bj;
                acc[g] = fmaf(av, sk, acc[g]);
            }
        }
#pragma unroll
        for (int g = 0; g < 4; ++g) red[w][l + 64 * g] = acc[g];
        __syncthreads();
        {
            float s = red[0][t] + red[1][t] + red[2][t] + red[3][t];
            if (which == 0)      uv[t]          = s * SC;
            else if (which == 1) wgf[2 * t]     = s * SC;
            else                 wgf[2 * t + 1] = s;
        }
    } else {
        const int j = t;
        float cq = in_w[j * EE + FF];
        float ck = in_w[(EE + j) * EE + FF];
        float cv = in_w[(2 * EE + j) * EE + FF];
        float rj = out_w[(EE - 1) * EE + j];
        float pa = cq * ck, pb = cv * rj;
        if (t == 0) {
            const int j2 = 256;
            pa += in_w[j2 * EE + FF] * in_w[(EE + j2) * EE + FF];
            pb += in_w[(2 * EE + j2) * EE + FF] * out_w[(EE - 1) * EE + j2];
        }
#pragma unroll
        for (int o = 32; o > 0; o >>= 1) {
            pa += __shfl_down(pa, o, 64);
            pb += __shfl_down(pb, o, 64);
        }
        if ((t & 63) == 0) { red[0][t >> 6] = pa; red[1][t >> 6] = pb; }
        __syncthreads();
        if (t == 0) {
            pa = red[0][0] + red[0][1] + red[0][2] + red[0][3];
            pb = red[1][0] + red[1][1] + red[1][2] + red[1][3];
            sc[0] = pa * SC;       // alpha (scaled, log2 domain)
            sc[1] = pb;            // beta  (value path, unscaled)
            sc[2] = out_b[EE - 1]; // ob
        }
    }
}

// ---------------- K2: per-batch attention, ki-sum split across waves (r22) ----------------
__global__ __launch_bounds__(256) void k2_attn(const float* __restrict__ x,
                                               const float2* __restrict__ mt2,
                                               const float* __restrict__ uv,
                                               const float* __restrict__ wg,   // interleaved (w,g) pairs
                                               const float* __restrict__ sc,
                                               float* __restrict__ xa) {
    const int t = threadIdx.x;
    const int w = t >> 6, l = t & 63;
    const int b0 = blockIdx.x * 2;
    __shared__ __align__(16) float xs0[FF];
    __shared__ __align__(16) float xs1[FF];
    __shared__ __align__(16) float wgs[2 * FF];
    __shared__ float rr[6][4][256];   // 24 KB partials (stride-1 per lane: conflict-free)
    xs0[t] = x[b0 * FF + t];
    xs1[t] = x[(b0 + 1) * FF + t];
    *(float2*)&wgs[2 * t] = *(const float2*)&wg[2 * t];
    const float alpha_s = sc[0], beta = sc[1], ob = sc[2];
    __syncthreads();
    float xq0[4], xq1[4], A0[4], A1[4];
#pragma unroll
    for (int g = 0; g < 4; ++g) {
        const int qi = l + 64 * g;
        const float u = uv[qi];
        xq0[g] = xs0[qi]; xq1[g] = xs1[qi];
        A0[g] = fmaf(alpha_s, xq0[g], u);
        A1[g] = fmaf(alpha_s, xq1[g], u);
    }
    float le0[4], le1[4], p0[4], p1[4], q0[4], q1[4];
#pragma unroll
    for (int g = 0; g < 4; ++g) { le0[g]=0.f; le1[g]=0.f; p0[g]=0.f; p1[g]=0.f; q0[g]=0.f; q1[g]=0.f; }
    const int kp0 = w * 32;            // this wave's 32 ki-pairs (64 ki)
#pragma unroll 2
    for (int kp = kp0; kp < kp0 + 32; ++kp) {
        const f32x4 wgk  = *(const f32x4*)&wgs[4 * kp];       // ds_read_b128 broadcast
        const float2 xk0 = *(const float2*)&xs0[2 * kp];      // ds_read_b64 broadcast
        const float2 xk1 = *(const float2*)&xs1[2 * kp];
#pragma unroll
        for (int g = 0; g < 4; ++g) {
            const float2 m = mt2[kp * FF + l + 64 * g];       // coalesced vmem 8B
            float e;
            e = EXP2(fmaf(xk0.x, A0[g], fmaf(wgk[0], xq0[g], m.x))); le0[g] += e; p0[g] = fmaf(e, wgk[1], p0[g]); q0[g] = fmaf(e, xk0.x, q0[g]);
            e = EXP2(fmaf(xk0.y, A0[g], fmaf(wgk[2], xq0[g], m.y))); le0[g] += e; p0[g] = fmaf(e, wgk[3], p0[g]); q0[g] = fmaf(e, xk0.y, q0[g]);
            e = EXP2(fmaf(xk1.x, A1[g], fmaf(wgk[0], xq1[g], m.x))); le1[g] += e; p1[g] = fmaf(e, wgk[1], p1[g]); q1[g] = fmaf(e, xk1.x, q1[g]);
            e = EXP2(fmaf(xk1.y, A1[g], fmaf(wgk[2], xq1[g], m.y))); le1[g] += e; p1[g] = fmaf(e, wgk[3], p1[g]); q1[g] = fmaf(e, xk1.y, q1[g]);
        }
    }
#pragma unroll
    for (int g = 0; g < 4; ++g) {
        const int qi = l + 64 * g;
        rr[0][w][qi] = le0[g]; rr[1][w][qi] = le1[g]; rr[2][w][qi] = p0[g];
        rr[3][w][qi] = p1[g];  rr[4][w][qi] = q0[g];  rr[5][w][qi] = q1[g];
    }
    __syncthreads();
    float LE0 = 0.f, LE1 = 0.f, P0 = 0.f, P1 = 0.f, Q0 = 0.f, Q1 = 0.f;
#pragma unroll
    for (int u2 = 0; u2 < 4; ++u2) {
        LE0 += rr[0][u2][t]; LE1 += rr[1][u2][t]; P0 += rr[2][u2][t];
        P1 += rr[3][u2][t];  Q0 += rr[4][u2][t];  Q1 += rr[5][u2][t];
    }
    xa[b0 * FF + t]       = (P0 + beta * Q0) / LE0 + ob;
    xa[(b0 + 1) * FF + t] = (P1 + beta * Q1) / LE1 + ob;
}

// ---------------- K3: r15 body, 2-chunk interleave at FULL occupancy ----------------
// Grid 768, (256,3), 3 blocks/CU (the 64.38 baseline's occupancy) with r19's 2-deep
// chunk interleave: BUILD(A)+BUILD(B) then EPI(A)+EPI(B) in one basic block -> 2x
// independent chains in every phase. Odd tail via clamped dummy (idempotent rewrite).
// Live set ~156 regs < (256,3) budget ~170 -> no spill (WRITE_SIZE is the tripwire).
__global__ __launch_bounds__(256, 3) void k3_fnn(const float* xa_in,  // aliases fo
                                                 const float* __restrict__ w1,
                                                 const float* __restrict__ b1,
                                                 const float* __restrict__ b2,
                                                 const float* __restrict__ b3,
                                                 const float* __restrict__ w4,
                                                 const float* __restrict__ b4,
                                                 const short* __restrict__ w2s,
                                                 const short* __restrict__ w3s,
                                                 float* fo) {
    const int fidx = blockIdx.x & 255;
    const int f   = ((fidx & 7) << 5) | (fidx >> 3);  // XCD x owns features [32x, 32x+32)
    const int rq  = blockIdx.x >> 8;   // 0..2 (same-f blocks 256 apart -> same XCD)
    const int tid = threadIdx.x;
    const int wv  = tid >> 6;
    const int l   = tid & 63;
    const int lr  = l & 15;
    const int lq  = l >> 4;

    const float* w1f = w1 + f * UU;
    const float* b1f = b1 + f * UU;
    const float* b2f = b2 + f * HH1;
    const float* b3f = b3 + f * HH2;
    const float* w4f = w4 + f * HH2;
    const short* w2sf = w2s + f * 8192;
    const short* w3sf = w3s + f * 4096;
    const float b4v  = b4[f];

    // chunk-invariant register preloads
    short8 W3h[2][2], W3l[2][2];
#pragma unroll
    for (int ct = 0; ct < 2; ++ct)
#pragma unroll
        for (int kb = 0; kb < 2; ++kb) {
            W3h[ct][kb] = *(const short8*)(w3sf + ((0 * 2 + kb) * 2 + ct) * 512 + l * 8);
            W3l[ct][kb] = *(const short8*)(w3sf + ((1 * 2 + kb) * 2 + ct) * 512 + l * 8);
        }
    f32x4 B3v[2], W4v[2];
#pragma unroll
    for (int ct = 0; ct < 2; ++ct) {
        B3v[ct] = *(const f32x4*)(b3f + ct * 16 + lq * 4);
        W4v[ct] = *(const f32x4*)(w4f + ct * 16 + lq * 4);
    }
    f32x4 B2v[4];
#pragma unroll
    for (int ht = 0; ht < 4; ++ht)
        B2v[ht] = *(const f32x4*)(b2f + (ht & 1) * 32 + lq * 8 + ((ht >> 1) << 2));

    // stage W2 frag block (16 KB) into LDS once
    __shared__ __align__(16) short w2l[8192];
#pragma unroll
    for (int i = 0; i < 4; ++i)
        *(short8*)(w2l + (tid * 4 + i) * 8) = *(const short8*)(w2sf + (tid * 4 + i) * 8);
    __syncthreads();

    // BUILD: layer1 (VALU) + layer2 (48 MFMA), pi-permuted layout -> acc[2][4]
    auto BUILD = [&](f32x4 (&acc)[2][4], float xv0, float xv1) {
        short8 Bh[2][2], Bl[2][2];   // [rbt][kb]
#pragma unroll
        for (int kb = 0; kb < 2; ++kb) {
            f32x4 wA = *(const f32x4*)(w1f + kb * 32 + lq * 8);
            f32x4 wB = *(const f32x4*)(w1f + kb * 32 + lq * 8 + 4);
            f32x4 bA = *(const f32x4*)(b1f + kb * 32 + lq * 8);
            f32x4 bB = *(const f32x4*)(b1f + kb * 32 + lq * 8 + 4);
#pragma unroll
            for (int rbt = 0; rbt < 2; ++rbt) {
                const float xv = rbt ? xv1 : xv0;
                float h[8];
#pragma unroll
                for (int j = 0; j < 4; ++j) h[j]     = fmaxf(fmaf(xv, wA[j], bA[j]), 0.f);
#pragma unroll
                for (int j = 0; j < 4; ++j) h[4 + j] = fmaxf(fmaf(xv, wB[j], bB[j]), 0.f);
                u32x4 bh, bl;
#pragma unroll
                for (int p = 0; p < 4; ++p) {
                    HiLo s = split2(h[2 * p], h[2 * p + 1]);
                    bh[p] = s.hi; bl[p] = s.lo;
                }
                Bh[rbt][kb] = __builtin_bit_cast(short8, bh);
                Bl[rbt][kb] = __builtin_bit_cast(short8, bl);
            }
        }
#pragma unroll
        for (int ht = 0; ht < 4; ++ht) {
            const short8 W2h0 = *(const short8*)(w2l + (0 * 4 + ht) * 512 + l * 8);
            const short8 W2h1 = *(const short8*)(w2l + (1 * 4 + ht) * 512 + l * 8);
            const short8 W2l0 = *(const short8*)(w2l + (2 * 4 + ht) * 512 + l * 8);
            const short8 W2l1 = *(const short8*)(w2l + (3 * 4 + ht) * 512 + l * 8);
#pragma unroll
            for (int rbt = 0; rbt < 2; ++rbt) {
                f32x4 a = B2v[ht];
                a = MF(W2h0, Bh[rbt][0], a);
                a = MF(W2h1, Bh[rbt][1], a);
                a = MF(W2h0, Bl[rbt][0], a);
                a = MF(W2h1, Bl[rbt][1], a);
                a = MF(W2l0, Bh[rbt][0], a);
                a = MF(W2l1, Bh[rbt][1], a);
                acc[rbt][ht] = a;
            }
        }
    };

    // EPI: relu -> layer3 B-frags (static reshuffle) -> layer3 (24 MFMA) -> w4 dot -> store
    auto EPI = [&](f32x4 (&acc)[2][4], int ch) {
        const int rows0 = ch * 32;
#pragma unroll
        for (int rbt = 0; rbt < 2; ++rbt) {
            short8 Bh3[2], Bl3[2];
#pragma unroll
            for (int kb = 0; kb < 2; ++kb) {
                float e0 = fmaxf(acc[rbt][kb][0], 0.f),     e1 = fmaxf(acc[rbt][kb][1], 0.f);
                float e2 = fmaxf(acc[rbt][kb][2], 0.f),     e3 = fmaxf(acc[rbt][kb][3], 0.f);
                float e4 = fmaxf(acc[rbt][kb + 2][0], 0.f), e5 = fmaxf(acc[rbt][kb + 2][1], 0.f);
                float e6 = fmaxf(acc[rbt][kb + 2][2], 0.f), e7 = fmaxf(acc[rbt][kb + 2][3], 0.f);
                HiLo p0 = split2(e0, e1), p1 = split2(e2, e3);
                HiLo p2 = split2(e4, e5), p3 = split2(e6, e7);
                u32x4 bh, bl;
                bh[0] = p0.hi; bh[1] = p1.hi; bh[2] = p2.hi; bh[3] = p3.hi;
                bl[0] = p0.lo; bl[1] = p1.lo; bl[2] = p2.lo; bl[3] = p3.lo;
                Bh3[kb] = __builtin_bit_cast(short8, bh);
                Bl3[kb] = __builtin_bit_cast(short8, bl);
            }
            float part = 0.f;
#pragma unroll
            for (int ct = 0; ct < 2; ++ct) {
                f32x4 a2 = B3v[ct];
                a2 = MF(W3h[ct][0], Bh3[0], a2);
                a2 = MF(W3h[ct][1], Bh3[1], a2);
                a2 = MF(W3h[ct][0], Bl3[0], a2);
                a2 = MF(W3h[ct][1], Bl3[1], a2);
                a2 = MF(W3l[ct][0], Bh3[0], a2);
                a2 = MF(W3l[ct][1], Bh3[1], a2);
#pragma unroll
                for (int r = 0; r < 4; ++r)
                    part = fmaf(fmaxf(a2[r], 0.f), W4v[ct][r], part);
            }
            part += __shfl_xor(part, 16, 64);
            part += __shfl_xor(part, 32, 64);
            if (lq == 0)
                fo[(rows0 + rbt * 16 + lr) * FF + f] = part + b4v;
        }
    };

    const int cstart = (rq * 64) / 3;        // 0,21,42
    const int cend   = ((rq + 1) * 64) / 3;  // 21,42,64
    int ch = cstart + wv;
    if (ch >= cend) return;
    f32x4 accA[2][4], accB[2][4];
    int chB = (ch + 4 < cend) ? ch + 4 : ch;
    float xvA0 = xa_in[(ch  * 32 + lr) * FF + f];
    float xvA1 = xa_in[(ch  * 32 + 16 + lr) * FF + f];
    float xvB0 = xa_in[(chB * 32 + lr) * FF + f];
    float xvB1 = xa_in[(chB * 32 + 16 + lr) * FF + f];
    for (; ch < cend; ) {
        const int chn = ch + 8;
        // prefetch next pair (hidden under this pair's body)
        float nA0 = 0.f, nA1 = 0.f, nB0 = 0.f, nB1 = 0.f;
        if (chn < cend) {
            const int chnB = (chn + 4 < cend) ? chn + 4 : chn;
            nA0 = xa_in[(chn  * 32 + lr) * FF + f];
            nA1 = xa_in[(chn  * 32 + 16 + lr) * FF + f];
            nB0 = xa_in[(chnB * 32 + lr) * FF + f];
            nB1 = xa_in[(chnB * 32 + 16 + lr) * FF + f];
        }
        BUILD(accA, xvA0, xvA1);
        BUILD(accB, xvB0, xvB1);
        EPI(accA, ch);
        EPI(accB, chB);          // dummy pair rewrites identical values (idempotent)
        xvA0 = nA0; xvA1 = nA1; xvB0 = nB0; xvB1 = nB1;
        ch = chn;
        chB = (ch + 4 < cend) ? ch + 4 : ch;
    }
}

// ---------------- K4: out[b] = sum_f fo[b,f] + bias ----------------
__global__ __launch_bounds__(64) void k4_sum(const float* __restrict__ fo,
                                             const float* __restrict__ bias,
                                             float* __restrict__ out) {
    const int b = blockIdx.x;
    const int t = threadIdx.x;  // 64
    const float* r = fo + b * FF;
    float s = r[t] + r[t + 64] + r[t + 128] + r[t + 192];
#pragma unroll
    for (int o = 32; o > 0; o >>= 1) s += __shfl_down(s, o, 64);
    if (t == 0) out[b] = s + bias[0];
}

extern "C" void kernel_launch(void* const* d_in, const int* in_sizes, int n_in,
                              void* d_out, int out_size, void* d_ws, size_t ws_size,
                              hipStream_t stream) {
    const float* x    = (const float*)d_in[0];
    const float* w1   = (const float*)d_in[1];
    const float* b1   = (const float*)d_in[2];
    const float* w2   = (const float*)d_in[3];
    const float* b2   = (const float*)d_in[4];
    const float* w3   = (const float*)d_in[5];
    const float* b3   = (const float*)d_in[6];
    const float* w4   = (const float*)d_in[7];
    const float* b4   = (const float*)d_in[8];
    const float* in_w = (const float*)d_in[9];
    const float* in_b = (const float*)d_in[10];
    const float* out_w= (const float*)d_in[11];
    const float* out_b= (const float*)d_in[12];
    const float* bias = (const float*)d_in[13];

    float* out = (float*)d_out;       // [B]
    float* fo  = out + BB;            // [B,F] — also used as xa buffer
    float* ws  = (float*)d_ws;
    float* mt  = ws;                  // 65536 floats (paired float2[128*256] layout)
    float* uvp = ws + 65536;          // 256
    float* wgp = ws + 65792;          // 512 (256 interleaved (w,g) pairs)
    float* scp = ws + 66304;          // 8
    short* w2s = (short*)(ws + 66560);            // 256 f * 8192 shorts (4 MB)
    short* w3s = w2s + 256 * 8192;                // 256 f * 4096 shorts (2 MB)

    k_prep<<<516, 256, 0, stream>>>(in_w, in_b, out_w, out_b, w2, w3,
                                    mt, uvp, wgp, scp, w2s, w3s);
    k2_attn<<<BB / 2, 256, 0, stream>>>(x, (const float2*)mt, uvp, wgp, scp, fo);
    k3_fnn<<<FF * 3, 256, 0, stream>>>(fo, w1, b1, b2, b3, w4, b4, w2s, w3s, fo);
    k4_sum<<<BB, 64, 0, stream>>>(fo, bias, out);
}

// Round 26
// 64.371 us; speedup vs baseline: 1.5730x; 1.5730x over previous
//
#include <hip/hip_runtime.h>

#define BB 2048
#define FF 256
#define EE 257
#define UU 64
#define HH1 64
#define HH2 32

// SC = log2(e) / sqrt(E): folds softmax temperature into log2-domain for exp2f
#define SC 0.089992807f

typedef __attribute__((ext_vector_type(8))) short short8;   // 8 bf16 (4 VGPR)
typedef __attribute__((ext_vector_type(4))) float f32x4;    // MFMA acc
typedef __attribute__((ext_vector_type(4))) unsigned u32x4;
typedef __attribute__((ext_vector_type(2))) unsigned u32x2;

#define MF(a, b, c) __builtin_amdgcn_mfma_f32_16x16x32_bf16(a, b, c, 0, 0, 0)
#define EXP2(x) __builtin_amdgcn_exp2f(x)   // bare v_exp_f32 (scores bounded, no fixup needed)

__device__ inline unsigned cvt_pk(float a, float b) {       // packed RNE: lo=bf16(a), hi=bf16(b)
    unsigned r;
    asm("v_cvt_pk_bf16_f32 %0, %1, %2" : "=v"(r) : "v"(a), "v"(b));
    return r;
}
struct HiLo { unsigned hi, lo; };
// hi/lo split of a pair: hi = bf16(a,b); lo = bf16(a-hi_a, b-hi_b)
__device__ inline HiLo split2(float a, float b) {
    HiLo r;
    r.hi = cvt_pk(a, b);
    float ha = __builtin_bit_cast(float, r.hi << 16);
    float hb = __builtin_bit_cast(float, r.hi & 0xFFFF0000u);
    r.lo = cvt_pk(a - ha, b - hb);
    return r;
}

// ---------------- K_prep (pair-packed mt, pi-permuted W2) ----------------
__global__ __launch_bounds__(256) void k_prep(const float* __restrict__ in_w,
                                              const float* __restrict__ in_b,
                                              const float* __restrict__ out_w,
                                              const float* __restrict__ out_b,
                                              const float* __restrict__ w2,
                                              const float* __restrict__ w3,
                                              float* __restrict__ mt,      // paired float2 layout
                                              float* __restrict__ uv, float* __restrict__ wgf,
                                              float* __restrict__ sc,
                                              short* __restrict__ w2s, short* __restrict__ w3s) {
    const int blk = blockIdx.x;
    const int t = threadIdx.x;
    __shared__ float red[4][256];
    __shared__ float s0[EE + 3];   // staged uniform stream A
    __shared__ float s1[EE + 3];   // staged uniform stream B
    if (blk < 256) {
        const int ki = blk;
        for (int j = t; j < EE; j += 256) {
            s0[j] = in_w[(EE + j) * EE + ki] + in_b[EE + j];
            s1[j] = in_b[j];
        }
        __syncthreads();
        const int w = t >> 6, l = t & 63;
        const int j0 = (w * EE) >> 2, j1 = ((w + 1) * EE) >> 2;
        float acc[4] = {0.f, 0.f, 0.f, 0.f};
#pragma unroll 4
        for (int j = j0; j < j1; ++j) {
            float ak = s0[j];   // LDS broadcast
            float bj = s1[j];
#pragma unroll
            for (int g = 0; g < 4; ++g) {
                float aq = in_w[j * EE + l + 64 * g] + bj;
                acc[g] = fmaf(aq, ak, acc[g]);
            }
        }
#pragma unroll
        for (int g = 0; g < 4; ++g) red[w][l + 64 * g] = acc[g];
        __syncthreads();
        {
            float s = red[0][t] + red[1][t] + red[2][t] + red[3][t];
            mt[(ki >> 1) * 512 + t * 2 + (ki & 1)] = s * SC;
        }
    } else if (blk < 512) {
        const int f = blk - 256;
        const int l = t & 63, q = t >> 6;
        const int lr = l & 15, lq = l >> 4;
        const float* w2f = w2 + f * (UU * HH1);
        const float* w3f = w3 + f * (HH1 * HH2);
        short* o2 = w2s + f * 8192;
        short* o3 = w3s + f * 4096;
        // pi-permuted h column for the W2 A-frag row (q = ht tile, lr = row-in-tile)
        const int hperm = (q & 1) * 32 + (lr >> 2) * 8 + ((q >> 1) << 2) + (lr & 3);
#pragma unroll
        for (int kb = 0; kb < 2; ++kb) {
            float v[8];
#pragma unroll
            for (int j = 0; j < 8; ++j) v[j] = w2f[(kb * 32 + lq * 8 + j) * HH1 + hperm];
            u32x4 hi, lo;
#pragma unroll
            for (int p = 0; p < 4; ++p) {
                HiLo s = split2(v[2 * p], v[2 * p + 1]);
                hi[p] = s.hi; lo[p] = s.lo;
            }
            *(short8*)(o2 + ((0 * 2 + kb) * 4 + q) * 512 + l * 8) = __builtin_bit_cast(short8, hi);
            *(short8*)(o2 + ((1 * 2 + kb) * 4 + q) * 512 + l * 8) = __builtin_bit_cast(short8, lo);
        }
        {
            const int kb = q & 1, ct = q >> 1;
            float v[8];
#pragma unroll
            for (int j = 0; j < 8; ++j) v[j] = w3f[(kb * 32 + lq * 8 + j) * HH2 + ct * 16 + lr];
            u32x4 hi, lo;
#pragma unroll
            for (int p = 0; p < 4; ++p) {
                HiLo s = split2(v[2 * p], v[2 * p + 1]);
                hi[p] = s.hi; lo[p] = s.lo;
            }
            *(short8*)(o3 + ((0 * 2 + kb) * 2 + ct) * 512 + l * 8) = __builtin_bit_cast(short8, hi);
            *(short8*)(o3 + ((1 * 2 + kb) * 2 + ct) * 512 + l * 8) = __builtin_bit_cast(short8, lo);
        }
    } else if (blk < 515) {
        const int which = blk - 512;
        for (int j = t; j < EE; j += 256) {
            if (which == 0)      { s0[j] = in_w[(EE + j) * EE + FF];    s1[j] = in_b[j]; }
            else if (which == 1) { s0[j] = in_w[j * EE + FF];           s1[j] = in_b[EE + j]; }
            else                 { s0[j] = out_w[(EE - 1) * EE + j];    s1[j] = in_b[2 * EE + j]; }
        }
        __syncthreads();
        const int w = t >> 6, l = t & 63;
        const int j0 = (w * EE) >> 2, j1 = ((w + 1) * EE) >> 2;
        const int rowbase = which * EE;
        float acc[4] = {0.f, 0.f, 0.f, 0.f};
#pragma unroll 4
        for (int j = j0; j < j1; ++j) {
            float sk = s0[j];
            float bj = s1[j];
#pragma unroll
            for (int g = 0; g < 4; ++g) {
                float av = in_w[(rowbase + j) * EE + l + 64 * g] + bj;
                acc[g] = fmaf(av, sk, acc[g]);
            }
        }
#pragma unroll
        for (int g = 0; g < 4; ++g) red[w][l + 64 * g] = acc[g];
        __syncthreads();
        {
            float s = red[0][t] + red[1][t] + red[2][t] + red[3][t];
            if (which == 0)      uv[t]          = s * SC;
            else if (which == 1) wgf[2 * t]     = s * SC;
            else                 wgf[2 * t + 1] = s;
        }
    } else {
        const int j = t;
        float cq = in_w[j * EE + FF];
        float ck = in_w[(EE + j) * EE + FF];
        float cv = in_w[(2 * EE + j) * EE + FF];
        float rj = out_w[(EE - 1) * EE + j];
        float pa = cq * ck, pb = cv * rj;
        if (t == 0) {
            const int j2 = 256;
            pa += in_w[j2 * EE + FF] * in_w[(EE + j2) * EE + FF];
            pb += in_w[(2 * EE + j2) * EE + FF] * out_w[(EE - 1) * EE + j2];
        }
#pragma unroll
        for (int o = 32; o > 0; o >>= 1) {
            pa += __shfl_down(pa, o, 64);
            pb += __shfl_down(pb, o, 64);
        }
        if ((t & 63) == 0) { red[0][t >> 6] = pa; red[1][t >> 6] = pb; }
        __syncthreads();
        if (t == 0) {
            pa = red[0][0] + red[0][1] + red[0][2] + red[0][3];
            pb = red[1][0] + red[1][1] + red[1][2] + red[1][3];
            sc[0] = pa * SC;       // alpha (scaled, log2 domain)
            sc[1] = pb;            // beta  (value path, unscaled)
            sc[2] = out_b[EE - 1]; // ob
        }
    }
}

// ---------------- K2: per-batch attention, ki-sum split across waves (r22) ----------------
__global__ __launch_bounds__(256) void k2_attn(const float* __restrict__ x,
                                               const float2* __restrict__ mt2,
                                               const float* __restrict__ uv,
                                               const float* __restrict__ wg,   // interleaved (w,g) pairs
                                               const float* __restrict__ sc,
                                               float* __restrict__ xa) {
    const int t = threadIdx.x;
    const int w = t >> 6, l = t & 63;
    const int b0 = blockIdx.x * 2;
    __shared__ __align__(16) float xs0[FF];
    __shared__ __align__(16) float xs1[FF];
    __shared__ __align__(16) float wgs[2 * FF];
    __shared__ float rr[6][4][256];   // 24 KB partials (stride-1 per lane: conflict-free)
    xs0[t] = x[b0 * FF + t];
    xs1[t] = x[(b0 + 1) * FF + t];
    *(float2*)&wgs[2 * t] = *(const float2*)&wg[2 * t];
    const float alpha_s = sc[0], beta = sc[1], ob = sc[2];
    __syncthreads();
    float xq0[4], xq1[4], A0[4], A1[4];
#pragma unroll
    for (int g = 0; g < 4; ++g) {
        const int qi = l + 64 * g;
        const float u = uv[qi];
        xq0[g] = xs0[qi]; xq1[g] = xs1[qi];
        A0[g] = fmaf(alpha_s, xq0[g], u);
        A1[g] = fmaf(alpha_s, xq1[g], u);
    }
    float le0[4], le1[4], p0[4], p1[4], q0[4], q1[4];
#pragma unroll
    for (int g = 0; g < 4; ++g) { le0[g]=0.f; le1[g]=0.f; p0[g]=0.f; p1[g]=0.f; q0[g]=0.f; q1[g]=0.f; }
    const int kp0 = w * 32;            // this wave's 32 ki-pairs (64 ki)
#pragma unroll 2
    for (int kp = kp0; kp < kp0 + 32; ++kp) {
        const f32x4 wgk  = *(const f32x4*)&wgs[4 * kp];       // ds_read_b128 broadcast
        const float2 xk0 = *(const float2*)&xs0[2 * kp];      // ds_read_b64 broadcast
        const float2 xk1 = *(const float2*)&xs1[2 * kp];
#pragma unroll
        for (int g = 0; g < 4; ++g) {
            const float2 m = mt2[kp * FF + l + 64 * g];       // coalesced vmem 8B
            float e;
            e = EXP2(fmaf(xk0.x, A0[g], fmaf(wgk[0], xq0[g], m.x))); le0[g] += e; p0[g] = fmaf(e, wgk[1], p0[g]); q0[g] = fmaf(e, xk0.x, q0[g]);
            e = EXP2(fmaf(xk0.y, A0[g], fmaf(wgk[2], xq0[g], m.y))); le0[g] += e; p0[g] = fmaf(e, wgk[3], p0[g]); q0[g] = fmaf(e, xk0.y, q0[g]);
            e = EXP2(fmaf(xk1.x, A1[g], fmaf(wgk[0], xq1[g], m.x))); le1[g] += e; p1[g] = fmaf(e, wgk[1], p1[g]); q1[g] = fmaf(e, xk1.x, q1[g]);
            e = EXP2(fmaf(xk1.y, A1[g], fmaf(wgk[2], xq1[g], m.y))); le1[g] += e; p1[g] = fmaf(e, wgk[3], p1[g]); q1[g] = fmaf(e, xk1.y, q1[g]);
        }
    }
#pragma unroll
    for (int g = 0; g < 4; ++g) {
        const int qi = l + 64 * g;
        rr[0][w][qi] = le0[g]; rr[1][w][qi] = le1[g]; rr[2][w][qi] = p0[g];
        rr[3][w][qi] = p1[g];  rr[4][w][qi] = q0[g];  rr[5][w][qi] = q1[g];
    }
    __syncthreads();
    float LE0 = 0.f, LE1 = 0.f, P0 = 0.f, P1 = 0.f, Q0 = 0.f, Q1 = 0.f;
#pragma unroll
    for (int u2 = 0; u2 < 4; ++u2) {
        LE0 += rr[0][u2][t]; LE1 += rr[1][u2][t]; P0 += rr[2][u2][t];
        P1 += rr[3][u2][t];  Q0 += rr[4][u2][t];  Q1 += rr[5][u2][t];
    }
    xa[b0 * FF + t]       = (P0 + beta * Q0) / LE0 + ob;
    xa[(b0 + 1) * FF + t] = (P1 + beta * Q1) / LE1 + ob;
}

// ---------------- K3: per-feature MLPs via split-bf16 MFMA, zero h2 LDS traffic (r15) ----------------
__global__ __launch_bounds__(256, 3) void k3_fnn(const float* xa_in,  // aliases fo
                                                 const float* __restrict__ w1,
                                                 const float* __restrict__ b1,
                                                 const float* __restrict__ b2,
                                                 const float* __restrict__ b3,
                                                 const float* __restrict__ w4,
                                                 const float* __restrict__ b4,
                                                 const short* __restrict__ w2s,
                                                 const short* __restrict__ w3s,
                                                 float* fo) {
    const int fidx = blockIdx.x & 255;
    const int f   = ((fidx & 7) << 5) | (fidx >> 3);  // XCD x owns features [32x, 32x+32)
    const int rq  = blockIdx.x >> 8;   // 0..2 (same-f blocks 256 apart -> same XCD)
    const int tid = threadIdx.x;
    const int wv  = tid >> 6;
    const int l   = tid & 63;
    const int lr  = l & 15;
    const int lq  = l >> 4;

    const float* w1f = w1 + f * UU;
    const float* b1f = b1 + f * UU;
    const float* b2f = b2 + f * HH1;
    const float* b3f = b3 + f * HH2;
    const float* w4f = w4 + f * HH2;
    const short* w2sf = w2s + f * 8192;
    const short* w3sf = w3s + f * 4096;
    const float b4v  = b4[f];

    // W3 frags (32 VGPR) + per-lane b3/w4/b2 vectors (chunk-invariant)
    short8 W3h[2][2], W3l[2][2];
#pragma unroll
    for (int ct = 0; ct < 2; ++ct)
#pragma unroll
        for (int kb = 0; kb < 2; ++kb) {
            W3h[ct][kb] = *(const short8*)(w3sf + ((0 * 2 + kb) * 2 + ct) * 512 + l * 8);
            W3l[ct][kb] = *(const short8*)(w3sf + ((1 * 2 + kb) * 2 + ct) * 512 + l * 8);
        }
    f32x4 B3v[2], W4v[2];
#pragma unroll
    for (int ct = 0; ct < 2; ++ct) {
        B3v[ct] = *(const f32x4*)(b3f + ct * 16 + lq * 4);
        W4v[ct] = *(const f32x4*)(w4f + ct * 16 + lq * 4);
    }
    f32x4 B2v[4];
#pragma unroll
    for (int ht = 0; ht < 4; ++ht)
        B2v[ht] = *(const f32x4*)(b2f + (ht & 1) * 32 + lq * 8 + ((ht >> 1) << 2));

    // stage W2 frag block (16 KB) into LDS once
    __shared__ __align__(16) short w2l[8192];
#pragma unroll
    for (int i = 0; i < 4; ++i)
        *(short8*)(w2l + (tid * 4 + i) * 8) = *(const short8*)(w2sf + (tid * 4 + i) * 8);
    __syncthreads();

    const int cstart = (rq * 64) / 3;        // 0,21,42
    const int cend   = ((rq + 1) * 64) / 3;  // 21,42,64
    int ch = cstart + wv;
    if (ch >= cend) return;
    float xv0 = xa_in[(ch * 32 + lr) * FF + f];
    float xv1 = xa_in[(ch * 32 + 16 + lr) * FF + f];
    for (; ch < cend; ch += 4) {
        const int rows0 = ch * 32;
        // prefetch next chunk's xv pair (hidden under this chunk's body)
        float nxv0 = 0.f, nxv1 = 0.f;
        if (ch + 4 < cend) {
            nxv0 = xa_in[((ch + 4) * 32 + lr) * FF + f];
            nxv1 = xa_in[((ch + 4) * 32 + 16 + lr) * FF + f];
        }

        // ---- layer1: h1T B-frags in registers (both 16-row tiles) ----
        short8 Bh[2][2], Bl[2][2];   // [rbt][kb]
#pragma unroll
        for (int kb = 0; kb < 2; ++kb) {
            f32x4 wA = *(const f32x4*)(w1f + kb * 32 + lq * 8);
            f32x4 wB = *(const f32x4*)(w1f + kb * 32 + lq * 8 + 4);
            f32x4 bA = *(const f32x4*)(b1f + kb * 32 + lq * 8);
            f32x4 bB = *(const f32x4*)(b1f + kb * 32 + lq * 8 + 4);
#pragma unroll
            for (int rbt = 0; rbt < 2; ++rbt) {
                const float xv = rbt ? xv1 : xv0;
                float h[8];
#pragma unroll
                for (int j = 0; j < 4; ++j) h[j]     = fmaxf(fmaf(xv, wA[j], bA[j]), 0.f);
#pragma unroll
                for (int j = 0; j < 4; ++j) h[4 + j] = fmaxf(fmaf(xv, wB[j], bB[j]), 0.f);
                u32x4 bh, bl;
#pragma unroll
                for (int p = 0; p < 4; ++p) {
                    HiLo s = split2(h[2 * p], h[2 * p + 1]);
                    bh[p] = s.hi; bl[p] = s.lo;
                }
                Bh[rbt][kb] = __builtin_bit_cast(short8, bh);
                Bl[rbt][kb] = __builtin_bit_cast(short8, bl);
            }
        }

        // ---- layer2T (pi-permuted rows): acc[rbt][ht] = h2[(ht&1)*32+lq*8+(ht>>1)*4+r][b] ----
        f32x4 acc[2][4];
#pragma unroll
        for (int ht = 0; ht < 4; ++ht) {
            const short8 W2h0 = *(const short8*)(w2l + (0 * 4 + ht) * 512 + l * 8);
            const short8 W2h1 = *(const short8*)(w2l + (1 * 4 + ht) * 512 + l * 8);
            const short8 W2l0 = *(const short8*)(w2l + (2 * 4 + ht) * 512 + l * 8);
            const short8 W2l1 = *(const short8*)(w2l + (3 * 4 + ht) * 512 + l * 8);
#pragma unroll
            for (int rbt = 0; rbt < 2; ++rbt) {
                f32x4 a = B2v[ht];
                a = MF(W2h0, Bh[rbt][0], a);
                a = MF(W2h1, Bh[rbt][1], a);
                a = MF(W2h0, Bl[rbt][0], a);
                a = MF(W2h1, Bl[rbt][1], a);
                a = MF(W2l0, Bh[rbt][0], a);
                a = MF(W2l1, Bh[rbt][1], a);
                acc[rbt][ht] = a;
            }
        }

        // ---- per 16-row tile: relu -> layer3 B-frags (static reshuffle) -> layer3T -> w4 dot ----
#pragma unroll
        for (int rbt = 0; rbt < 2; ++rbt) {
            short8 Bh3[2], Bl3[2];
#pragma unroll
            for (int kb = 0; kb < 2; ++kb) {
                float e0 = fmaxf(acc[rbt][kb][0], 0.f),     e1 = fmaxf(acc[rbt][kb][1], 0.f);
                float e2 = fmaxf(acc[rbt][kb][2], 0.f),     e3 = fmaxf(acc[rbt][kb][3], 0.f);
                float e4 = fmaxf(acc[rbt][kb + 2][0], 0.f), e5 = fmaxf(acc[rbt][kb + 2][1], 0.f);
                float e6 = fmaxf(acc[rbt][kb + 2][2], 0.f), e7 = fmaxf(acc[rbt][kb + 2][3], 0.f);
                HiLo p0 = split2(e0, e1), p1 = split2(e2, e3);
                HiLo p2 = split2(e4, e5), p3 = split2(e6, e7);
                u32x4 bh, bl;
                bh[0] = p0.hi; bh[1] = p1.hi; bh[2] = p2.hi; bh[3] = p3.hi;
                bl[0] = p0.lo; bl[1] = p1.lo; bl[2] = p2.lo; bl[3] = p3.lo;
                Bh3[kb] = __builtin_bit_cast(short8, bh);
                Bl3[kb] = __builtin_bit_cast(short8, bl);
            }
            float part = 0.f;
#pragma unroll
            for (int ct = 0; ct < 2; ++ct) {
                f32x4 a2 = B3v[ct];
                a2 = MF(W3h[ct][0], Bh3[0], a2);
                a2 = MF(W3h[ct][1], Bh3[1], a2);
                a2 = MF(W3h[ct][0], Bl3[0], a2);
                a2 = MF(W3h[ct][1], Bl3[1], a2);
                a2 = MF(W3l[ct][0], Bh3[0], a2);
                a2 = MF(W3l[ct][1], Bh3[1], a2);
#pragma unroll
                for (int r = 0; r < 4; ++r)
                    part = fmaf(fmaxf(a2[r], 0.f), W4v[ct][r], part);
            }
            part += __shfl_xor(part, 16, 64);
            part += __shfl_xor(part, 32, 64);
            if (lq == 0)
                fo[(rows0 + rbt * 16 + lr) * FF + f] = part + b4v;
        }

        xv0 = nxv0; xv1 = nxv1;
    }
}

// ---------------- K4: out[b] = sum_f fo[b,f] + bias ----------------
__global__ __launch_bounds__(64) void k4_sum(const float* __restrict__ fo,
                                             const float* __restrict__ bias,
                                             float* __restrict__ out) {
    const int b = blockIdx.x;
    const int t = threadIdx.x;  // 64
    const float* r = fo + b * FF;
    float s = r[t] + r[t + 64] + r[t + 128] + r[t + 192];
#pragma unroll
    for (int o = 32; o > 0; o >>= 1) s += __shfl_down(s, o, 64);
    if (t == 0) out[b] = s + bias[0];
}

extern "C" void kernel_launch(void* const* d_in, const int* in_sizes, int n_in,
                              void* d_out, int out_size, void* d_ws, size_t ws_size,
                              hipStream_t stream) {
    const float* x    = (const float*)d_in[0];
    const float* w1   = (const float*)d_in[1];
    const float* b1   = (const float*)d_in[2];
    const float* w2   = (const float*)d_in[3];
    const float* b2   = (const float*)d_in[4];
    const float* w3   = (const float*)d_in[5];
    const float* b3   = (const float*)d_in[6];
    const float* w4   = (const float*)d_in[7];
    const float* b4   = (const float*)d_in[8];
    const float* in_w = (const float*)d_in[9];
    const float* in_b = (const float*)d_in[10];
    const float* out_w= (const float*)d_in[11];
    const float* out_b= (const float*)d_in[12];
    const float* bias = (const float*)d_in[13];

    float* out = (float*)d_out;       // [B]
    float* fo  = out + BB;            // [B,F] — also used as xa buffer
    float* ws  = (float*)d_ws;
    float* mt  = ws;                  // 65536 floats (paired float2[128*256] layout)
    float* uvp = ws + 65536;          // 256
    float* wgp = ws + 65792;          // 512 (256 interleaved (w,g) pairs)
    float* scp = ws + 66304;          // 8
    short* w2s = (short*)(ws + 66560);            // 256 f * 8192 shorts (4 MB)
    short* w3s = w2s + 256 * 8192;                // 256 f * 4096 shorts (2 MB)

    k_prep<<<516, 256, 0, stream>>>(in_w, in_b, out_w, out_b, w2, w3,
                                    mt, uvp, wgp, scp, w2s, w3s);
    k2_attn<<<BB / 2, 256, 0, stream>>>(x, (const float2*)mt, uvp, wgp, scp, fo);
    k3_fnn<<<FF * 3, 256, 0, stream>>>(fo, w1, b1, b2, b3, w4, b4, w2s, w3s, fo);
    k4_sum<<<BB, 64, 0, stream>>>(fo, bias, out);
}